// Round 5
// baseline (97.415 us; speedup 1.0000x reference)
//
#include <hip/hip_runtime.h>
#include <math.h>

#define N 8192
#define D 3072

typedef float f4 __attribute__((ext_vector_type(4)));

// Kernel 1: one WAVE per row (4 rows per 256-thread block, no LDS, no barrier).
// One pass over x: row sum S and dot(x[i,:], w). Epilogue: e[i]=exp(S),
// r[i]=exp(-S). e stored at ws+1 so e+j is 16B-aligned for j ≡ 3 (mod 4).
__global__ __launch_bounds__(256) void rowsum_dot_kernel(
    const float* __restrict__ x, const float* __restrict__ w,
    float* __restrict__ ws_e, float* __restrict__ r,
    float* __restrict__ pred) {
    const int wave = threadIdx.x >> 6;
    const int lane = threadIdx.x & 63;
    const int i = blockIdx.x * 4 + wave;
    const float* xrow = x + (size_t)i * D;

    float sum = 0.f, dot = 0.f;
    #pragma unroll
    for (int k = 0; k < 12; ++k) {
        const int idx = (k * 64 + lane) * 4;
        const f4 xv = *reinterpret_cast<const f4*>(xrow + idx);
        const f4 wv = *reinterpret_cast<const f4*>(w + idx);
        sum += (xv.x + xv.y) + (xv.z + xv.w);
        dot += xv.x * wv.x + xv.y * wv.y + xv.z * wv.z + xv.w * wv.w;
    }
    #pragma unroll
    for (int off = 32; off > 0; off >>= 1) {
        sum += __shfl_down(sum, off, 64);
        dot += __shfl_down(dot, off, 64);
    }
    if (lane == 0) {
        ws_e[1 + i] = __expf(sum);   // e[i]
        r[i]        = __expf(-sum);  // exp(-s[i])
        pred[i]     = dot + w[D];    // + bias
    }
}

// Kernel 2: fused K-matrix + loss.
// Block 0: loss reduction (tiny, hides under the store stream).
// Blocks 1..1024: 8 consecutive rows each (256KB contiguous region).
//   Preload this thread's 8 e-chunks into registers ONCE, then emit
//   8 rows x 8 dependency-free float4 stores (fill-kernel-shaped).
//   K row base ≡ 1 (mod 4 floats): peel 3-head + 1-tail per row.
__global__ __launch_bounds__(256) void kmat_loss_kernel(
    const float* __restrict__ ws_e, const float* __restrict__ r,
    float* __restrict__ Kf /* = d_out + 8193 */,
    const float* __restrict__ pred, const int* __restrict__ y,
    const float* __restrict__ w, float* __restrict__ loss_out) {
    const int tid = threadIdx.x;
    const float* __restrict__ e = ws_e + 1;

    if (blockIdx.x == 0) {
        float acc = 0.f;
        for (int i = tid; i < N; i += 256) {
            const float d = (float)y[i] - pred[i];
            acc += d * d;
        }
        float wacc = 0.f;
        for (int i = tid; i < D + 1; i += 256) wacc += fabsf(w[i]);
        #pragma unroll
        for (int off = 32; off > 0; off >>= 1) {
            acc  += __shfl_down(acc, off, 64);
            wacc += __shfl_down(wacc, off, 64);
        }
        __shared__ float la[4], lw[4];
        const int wv = tid >> 6;
        if ((tid & 63) == 0) { la[wv] = acc; lw[wv] = wacc; }
        __syncthreads();
        if (tid == 0) {
            const float a = (la[0] + la[1]) + (la[2] + la[3]);
            const float b = (lw[0] + lw[1]) + (lw[2] + lw[3]);
            loss_out[0] = 0.5f * sqrtf(a) / (float)N + b;
        }
        return;
    }

    const int i0 = (blockIdx.x - 1) * 8;

    // Preload e-chunks: thread t owns chunks c = t + 256k, k=0..7 (c < 2047).
    f4 ev[8];
    #pragma unroll
    for (int k = 0; k < 8; ++k) {
        const int c = tid + 256 * k;
        if (c < 2047) ev[k] = *reinterpret_cast<const f4*>(e + 3 + 4 * c);
    }
    float eh0 = 0.f, eh1 = 0.f, eh2 = 0.f, et = 0.f;
    if (tid == 0) { eh0 = e[0]; eh1 = e[1]; eh2 = e[2]; }
    if (tid == 1) et = e[N - 1];

    #pragma unroll
    for (int rr = 0; rr < 8; ++rr) {
        const int i = i0 + rr;
        const float ri = r[i];  // block-uniform -> scalar load
        float* __restrict__ row = Kf + (size_t)i * N;
        if (tid == 0) { row[0] = eh0 * ri; row[1] = eh1 * ri; row[2] = eh2 * ri; }
        if (tid == 1) row[N - 1] = et * ri;
        #pragma unroll
        for (int k = 0; k < 8; ++k) {
            const int c = tid + 256 * k;
            if (c < 2047)
                *reinterpret_cast<f4*>(row + 3 + 4 * c) = ev[k] * ri;
        }
    }
}

extern "C" void kernel_launch(void* const* d_in, const int* in_sizes, int n_in,
                              void* d_out, int out_size, void* d_ws, size_t ws_size,
                              hipStream_t stream) {
    const float* x = (const float*)d_in[0];   // [8192, 3072] f32
    const int*   y = (const int*)d_in[1];     // [8192, 1] i32
    const float* w = (const float*)d_in[2];   // [3073, 1] f32

    float* out  = (float*)d_out;
    float* pred = out;              // [8192]
    float* loss = out + N;          // [1]
    float* Kf   = out + N + 1;      // [8192, 8192], base ≡ 1 (mod 4 floats)

    float* ws_e = (float*)d_ws;     // e[i] at ws_e[1+i]
    float* r    = ws_e + 8200;      // [8192]

    rowsum_dot_kernel<<<N / 4, 256, 0, stream>>>(x, w, ws_e, r, pred);
    kmat_loss_kernel<<<1025, 256, 0, stream>>>(ws_e, r, Kf, pred, y, w, loss);
}